// Round 1
// baseline (820.526 us; speedup 1.0000x reference)
//
#include <hip/hip_runtime.h>
#include <hip/hip_bf16.h>

#define N_ 4
#define C_ 512
#define CI_ 256
#define S_ 6272
#define EPS_ 1e-5f

typedef __attribute__((ext_vector_type(8))) __bf16 bf16x8;
typedef __attribute__((ext_vector_type(4))) __bf16 bf16x4;
typedef __attribute__((ext_vector_type(4))) float f32x4;

#define MFMA(a, b, c) __builtin_amdgcn_mfma_f32_16x16x32_bf16(a, b, c, 0, 0, 0)

// ---------------- Kernel 1: QKV projections ----------------
// Orientation: M = ci, N = s, K = c.  Outputs:
//   theta[n][s][ci], phi[n][s][ci] (bf16)   gT[n][ci][s] (bf16)
__global__ __launch_bounds__(256) void qkv_kernel(
    const float* __restrict__ x,
    const float* __restrict__ w_theta, const float* __restrict__ b_theta,
    const float* __restrict__ w_phi,   const float* __restrict__ b_phi,
    const float* __restrict__ w_g,     const float* __restrict__ b_g,
    __bf16* __restrict__ theta, __bf16* __restrict__ phi, __bf16* __restrict__ gT)
{
    const int s0  = blockIdx.x * 64;
    const int ci0 = blockIdx.y * 64;
    const int n   = blockIdx.z;
    const int tid = threadIdx.x;
    const int wave = tid >> 6, lane = tid & 63;
    const int m16 = lane & 15, quad = lane >> 4;

    __shared__ __bf16 xT[64][40];  // [s-local][c-local(32)], pad->40 (2-way banks, 16B-aligned rows)

    const float* wptr[3] = {w_theta, w_phi, w_g};

    f32x4 acc[3][4];
    #pragma unroll
    for (int j = 0; j < 3; ++j)
        #pragma unroll
        for (int ss = 0; ss < 4; ++ss) acc[j][ss] = f32x4{0.f, 0.f, 0.f, 0.f};

    const int ci_row = ci0 + wave * 16 + m16;  // A-frag row (M index)

    for (int kc = 0; kc < 16; ++kc) {
        __syncthreads();  // protect previous iteration's xT reads
        // stage x[n][kc*32+cc][s0+ss] -> xT[ss][cc] (coalesced along s)
        #pragma unroll
        for (int it = 0; it < 8; ++it) {
            int idx = it * 256 + tid;
            int cc = idx >> 6, ss = idx & 63;
            float v = x[((size_t)n * C_ + (size_t)kc * 32 + cc) * S_ + s0 + ss];
            xT[ss][cc] = (__bf16)v;
        }
        __syncthreads();

        bf16x8 afr[3];
        #pragma unroll
        for (int j = 0; j < 3; ++j) {
            const float* wp = wptr[j] + (size_t)ci_row * C_ + kc * 32 + quad * 8;
            bf16x8 t;
            #pragma unroll
            for (int e = 0; e < 8; ++e) t[e] = (__bf16)wp[e];
            afr[j] = t;
        }
        #pragma unroll
        for (int ss = 0; ss < 4; ++ss) {
            bf16x8 bfr = *(const bf16x8*)&xT[ss * 16 + m16][quad * 8];
            #pragma unroll
            for (int j = 0; j < 3; ++j)
                acc[j][ss] = MFMA(afr[j], bfr, acc[j][ss]);
        }
    }

    // C layout: col = s (per frag: ss*16+m16), rows = ci0+wave*16+quad*4+r
    const int ci_base = ci0 + wave * 16 + quad * 4;
    float bth[4], bph[4], bgg[4];
    #pragma unroll
    for (int r = 0; r < 4; ++r) {
        bth[r] = b_theta[ci_base + r];
        bph[r] = b_phi[ci_base + r];
        bgg[r] = b_g[ci_base + r];
    }
    #pragma unroll
    for (int ss = 0; ss < 4; ++ss) {
        int s = s0 + ss * 16 + m16;
        bf16x4 tv, pv;
        #pragma unroll
        for (int r = 0; r < 4; ++r) {
            tv[r] = (__bf16)(acc[0][ss][r] + bth[r]);
            pv[r] = (__bf16)(acc[1][ss][r] + bph[r]);
        }
        *(bf16x4*)&theta[((size_t)n * S_ + s) * CI_ + ci_base] = tv;
        *(bf16x4*)&phi[((size_t)n * S_ + s) * CI_ + ci_base]   = pv;
        #pragma unroll
        for (int r = 0; r < 4; ++r)
            gT[((size_t)n * CI_ + ci_base + r) * S_ + s] = (__bf16)(acc[2][ss][r] + bgg[r]);
    }
}

// ---------------- Kernel 2: flash attention ----------------
// Per block: 64 queries (4 waves x 16), loop over 98 key-tiles of 64.
// Transposed MFMA: scores^T (A=K, B=Q) -> per-lane scalar softmax state.
__global__ __launch_bounds__(256) void attn_kernel(
    const __bf16* __restrict__ theta, const __bf16* __restrict__ phi,
    const __bf16* __restrict__ gT, __bf16* __restrict__ O)
{
    const int q0 = blockIdx.x * 64;
    const int n  = blockIdx.y;
    const int tid = threadIdx.x;
    const int wave = tid >> 6, lane = tid & 63;
    const int m16 = lane & 15, quad = lane >> 4;

    extern __shared__ char smem[];
    __bf16* k_lds = (__bf16*)smem;                               // [64][264]
    __bf16* v_lds = (__bf16*)(smem + 64 * 264 * 2);              // [256][72]
    __bf16* p_lds = (__bf16*)(smem + 64 * 264 * 2 + 256 * 72 * 2) + wave * 16 * 72;  // [16][72]/wave

    // Q as B-frags: lane n=m16 -> q; k = kk*32 + quad*8 + j
    const int q = q0 + wave * 16 + m16;
    bf16x8 qf[8];
    const __bf16* qrow = theta + ((size_t)n * S_ + q) * CI_ + quad * 8;
    #pragma unroll
    for (int kk = 0; kk < 8; ++kk) qf[kk] = *(const bf16x8*)(qrow + kk * 32);

    f32x4 o[16];
    #pragma unroll
    for (int c = 0; c < 16; ++c) o[c] = f32x4{0.f, 0.f, 0.f, 0.f};
    float m_run = -1e30f, l_run = 0.0f;

    for (int kt = 0; kt < 98; ++kt) {
        const int p0 = kt * 64;
        #pragma unroll
        for (int it = 0; it < 8; ++it) {   // K tile: phi[p0+row][ci] -> k_lds[row][ci]
            int idx = it * 256 + tid;
            int row = idx >> 5, ch = idx & 31;
            *(uint4*)&k_lds[row * 264 + ch * 8] =
                *(const uint4*)&phi[((size_t)n * S_ + p0 + row) * CI_ + ch * 8];
        }
        #pragma unroll
        for (int it = 0; it < 8; ++it) {   // V tile: gT[ci][p0+key] -> v_lds[ci][key]
            int idx = it * 256 + tid;
            int ci = idx >> 3, ch = idx & 7;
            *(uint4*)&v_lds[ci * 72 + ch * 8] =
                *(const uint4*)&gT[((size_t)n * CI_ + ci) * S_ + p0 + ch * 8];
        }
        __syncthreads();

        // scores^T: D[m=key][n=q]
        f32x4 sc[4];
        #pragma unroll
        for (int sub = 0; sub < 4; ++sub) {
            f32x4 a = f32x4{0.f, 0.f, 0.f, 0.f};
            #pragma unroll
            for (int kk = 0; kk < 8; ++kk) {
                bf16x8 kf = *(const bf16x8*)&k_lds[(sub * 16 + m16) * 264 + kk * 32 + quad * 8];
                a = MFMA(kf, qf[kk], a);
            }
            sc[sub] = a;
        }
        // online softmax along keys (lane's column q); 16 scores/lane
        float vmax = -1e30f;
        #pragma unroll
        for (int sub = 0; sub < 4; ++sub)
            #pragma unroll
            for (int r = 0; r < 4; ++r) {
                sc[sub][r] *= 0.0625f;  // ci^-0.5 = 1/16
                vmax = fmaxf(vmax, sc[sub][r]);
            }
        vmax = fmaxf(vmax, __shfl_xor(vmax, 16));
        vmax = fmaxf(vmax, __shfl_xor(vmax, 32));
        float m_new = fmaxf(m_run, vmax);
        float alpha = __expf(m_run - m_new);
        float psum = 0.0f;
        float pvv[16];
        #pragma unroll
        for (int sub = 0; sub < 4; ++sub)
            #pragma unroll
            for (int r = 0; r < 4; ++r) {
                float e = __expf(sc[sub][r] - m_new);
                pvv[sub * 4 + r] = e;
                psum += e;
            }
        psum += __shfl_xor(psum, 16);
        psum += __shfl_xor(psum, 32);
        l_run = l_run * alpha + psum;
        m_run = m_new;
        #pragma unroll
        for (int c = 0; c < 16; ++c) {
            o[c][0] *= alpha; o[c][1] *= alpha; o[c][2] *= alpha; o[c][3] *= alpha;
        }
        // P -> LDS in [q][key] layout (rows key = sub*16+quad*4+r, col = own q)
        #pragma unroll
        for (int sub = 0; sub < 4; ++sub) {
            bf16x4 pk;
            #pragma unroll
            for (int r = 0; r < 4; ++r) pk[r] = (__bf16)pvv[sub * 4 + r];
            *(bf16x4*)&p_lds[m16 * 72 + sub * 16 + quad * 4] = pk;
        }
        __syncthreads();

        // PV: D[m=ci][n=q]; A = v_lds[ci][key], B = p_lds[q][key]
        bf16x8 pf0 = *(const bf16x8*)&p_lds[m16 * 72 + quad * 8];
        bf16x8 pf1 = *(const bf16x8*)&p_lds[m16 * 72 + 32 + quad * 8];
        #pragma unroll
        for (int c = 0; c < 16; ++c) {
            bf16x8 vf0 = *(const bf16x8*)&v_lds[(c * 16 + m16) * 72 + quad * 8];
            bf16x8 vf1 = *(const bf16x8*)&v_lds[(c * 16 + m16) * 72 + 32 + quad * 8];
            o[c] = MFMA(vf0, pf0, o[c]);
            o[c] = MFMA(vf1, pf1, o[c]);
        }
        __syncthreads();
    }

    // O^T C-layout: col = q, rows ci = c*16 + quad*4 + r.  Store O[n][s][ci] bf16.
    float inv_l = 1.0f / l_run;
    #pragma unroll
    for (int c = 0; c < 16; ++c) {
        bf16x4 ov;
        #pragma unroll
        for (int r = 0; r < 4; ++r) ov[r] = (__bf16)(o[c][r] * inv_l);
        *(bf16x4*)&O[((size_t)n * S_ + q) * CI_ + c * 16 + quad * 4] = ov;
    }
}

// ---------------- Kernel 3: w_out GEMM + BN partial stats ----------------
// p[n][c][s] = sum_ci w_out[c][ci] * O[n][s][ci] + b_out[c]   (bf16 out)
__global__ __launch_bounds__(256) void pgemm_kernel(
    const __bf16* __restrict__ O, const float* __restrict__ w_out,
    const float* __restrict__ b_out,
    __bf16* __restrict__ p, float* __restrict__ ssum, float* __restrict__ ssq)
{
    const int s0 = blockIdx.x * 64;
    const int c0 = blockIdx.y * 64;
    const int n  = blockIdx.z;
    const int tid = threadIdx.x;
    const int wave = tid >> 6, lane = tid & 63;
    const int m16 = lane & 15, quad = lane >> 4;

    __shared__ __bf16 o_lds[64][264];

    #pragma unroll
    for (int it = 0; it < 8; ++it) {
        int idx = it * 256 + tid;
        int row = idx >> 5, ch = idx & 31;
        *(uint4*)&o_lds[row][ch * 8] =
            *(const uint4*)&O[((size_t)n * S_ + s0 + row) * CI_ + ch * 8];
    }
    __syncthreads();

    const int c_row = c0 + wave * 16 + m16;
    bf16x8 af[8];
    #pragma unroll
    for (int kk = 0; kk < 8; ++kk) {
        const float* wp = w_out + (size_t)c_row * CI_ + kk * 32 + quad * 8;
        bf16x8 t;
        #pragma unroll
        for (int e = 0; e < 8; ++e) t[e] = (__bf16)wp[e];
        af[kk] = t;
    }
    f32x4 acc[4];
    #pragma unroll
    for (int ss = 0; ss < 4; ++ss) acc[ss] = f32x4{0.f, 0.f, 0.f, 0.f};
    #pragma unroll
    for (int ss = 0; ss < 4; ++ss)
        #pragma unroll
        for (int kk = 0; kk < 8; ++kk) {
            bf16x8 bfr = *(const bf16x8*)&o_lds[ss * 16 + m16][kk * 32 + quad * 8];
            acc[ss] = MFMA(af[kk], bfr, acc[ss]);
        }

    const int c_base = c0 + wave * 16 + quad * 4;
    float bo[4];
    #pragma unroll
    for (int r = 0; r < 4; ++r) bo[r] = b_out[c_base + r];
    float psum[4] = {0.f, 0.f, 0.f, 0.f}, psq[4] = {0.f, 0.f, 0.f, 0.f};
    #pragma unroll
    for (int ss = 0; ss < 4; ++ss) {
        int s = s0 + ss * 16 + m16;
        #pragma unroll
        for (int r = 0; r < 4; ++r) {
            float v = acc[ss][r] + bo[r];
            __bf16 vb = (__bf16)v;
            p[((size_t)n * C_ + c_base + r) * S_ + s] = vb;
            float vr = (float)vb;  // stats on rounded value: self-consistent BN
            psum[r] += vr;
            psq[r]  += vr * vr;
        }
    }
    #pragma unroll
    for (int r = 0; r < 4; ++r) {
        #pragma unroll
        for (int off = 1; off < 16; off <<= 1) {
            psum[r] += __shfl_xor(psum[r], off);
            psq[r]  += __shfl_xor(psq[r], off);
        }
    }
    if (m16 == 0) {
        #pragma unroll
        for (int r = 0; r < 4; ++r) {
            atomicAdd(&ssum[c_base + r], psum[r]);
            atomicAdd(&ssq[c_base + r],  psq[r]);
        }
    }
}

// ---------------- small kernels ----------------
__global__ void zero_stats(float* ptr) {
    ptr[blockIdx.x * blockDim.x + threadIdx.x] = 0.0f;
}

__global__ void stats_kernel(const float* __restrict__ ssum, const float* __restrict__ ssq,
                             const float* __restrict__ gamma, const float* __restrict__ beta,
                             float* __restrict__ sc, float* __restrict__ sh)
{
    int c = threadIdx.x;  // 512
    const float inv_m = 1.0f / (float)((size_t)N_ * S_);
    float mean = ssum[c] * inv_m;
    float var = ssq[c] * inv_m - mean * mean;
    var = fmaxf(var, 0.0f);
    float inv = rsqrtf(var + EPS_);
    float g = gamma[c];
    sc[c] = inv * g;
    sh[c] = beta[c] - mean * inv * g;
}

__global__ __launch_bounds__(256) void apply_kernel(
    const float* __restrict__ x, const __bf16* __restrict__ p,
    const float* __restrict__ sc, const float* __restrict__ sh,
    float* __restrict__ out)
{
    size_t i4 = (size_t)blockIdx.x * blockDim.x + threadIdx.x;
    size_t base = i4 * 4;
    int c = (int)((base / S_) % C_);
    float4 xv = *(const float4*)(x + base);
    bf16x4 pv = *(const bf16x4*)(p + base);
    float s = sc[c], h = sh[c];
    float4 ov;
    ov.x = xv.x + (float)pv[0] * s + h;
    ov.y = xv.y + (float)pv[1] * s + h;
    ov.z = xv.z + (float)pv[2] * s + h;
    ov.w = xv.w + (float)pv[3] * s + h;
    *(float4*)(out + base) = ov;
}

extern "C" void kernel_launch(void* const* d_in, const int* in_sizes, int n_in,
                              void* d_out, int out_size, void* d_ws, size_t ws_size,
                              hipStream_t stream)
{
    const float* x       = (const float*)d_in[0];
    const float* w_theta = (const float*)d_in[1];
    const float* b_theta = (const float*)d_in[2];
    const float* w_phi   = (const float*)d_in[3];
    const float* b_phi   = (const float*)d_in[4];
    const float* w_g     = (const float*)d_in[5];
    const float* b_g     = (const float*)d_in[6];
    const float* w_out   = (const float*)d_in[7];
    const float* b_out   = (const float*)d_in[8];
    const float* gamma   = (const float*)d_in[9];
    const float* beta    = (const float*)d_in[10];

    char* ws = (char*)d_ws;
    const size_t sz_qkv = (size_t)N_ * S_ * CI_ * 2;  // 12,845,056 B
    __bf16* theta = (__bf16*)(ws);
    __bf16* phi   = (__bf16*)(ws + sz_qkv);
    __bf16* gT    = (__bf16*)(ws + 2 * sz_qkv);
    __bf16* O     = (__bf16*)(ws + 3 * sz_qkv);
    __bf16* p     = (__bf16*)(ws + 4 * sz_qkv);
    float* ssum   = (float*)(ws + 4 * sz_qkv + (size_t)N_ * C_ * S_ * 2);
    float* ssq = ssum + 512;
    float* scv = ssum + 1024;
    float* shv = ssum + 1536;

    zero_stats<<<1, 1024, 0, stream>>>(ssum);
    qkv_kernel<<<dim3(98, 4, 4), 256, 0, stream>>>(
        x, w_theta, b_theta, w_phi, b_phi, w_g, b_g, theta, phi, gT);
    hipFuncSetAttribute((const void*)attn_kernel,
                        hipFuncAttributeMaxDynamicSharedMemorySize, 79872);
    attn_kernel<<<dim3(98, 4), 256, 79872, stream>>>(theta, phi, gT, O);
    pgemm_kernel<<<dim3(98, 8, 4), 256, 0, stream>>>(O, w_out, b_out, p, ssum, ssq);
    stats_kernel<<<1, 512, 0, stream>>>(ssum, ssq, gamma, beta, scv, shv);
    apply_kernel<<<12544, 256, 0, stream>>>(x, p, scv, shv, (float*)d_out);
}